// Round 2
// baseline (165.292 us; speedup 1.0000x reference)
//
#include <hip/hip_runtime.h>
#include <hip/hip_bf16.h>
#include <math.h>

// Problem constants
#define Bdim 2
#define Tdim 512
#define Cdim 256
#define Hdim 8
#define Edim 32
#define NTYPES 16
#define TI 8       // i-tile size
#define JT 128     // j-tile size

// ---------------------------------------------------------------------------
// Kernel 1: fused edge-tables + qkv GEMM.
// blocks 0..383: qkv GEMM (M=1024,K=256,N=768), 32x64 tile, scatter (B,H,T,E)
// blocks 384..399: ekt/evt = emb[t] @ w_edge_{k,v}
// ---------------------------------------------------------------------------
__global__ __launch_bounds__(256) void pre_kernel(
    const float* __restrict__ A, const float* __restrict__ Bw,
    const float* __restrict__ emb, const float* __restrict__ wk,
    const float* __restrict__ wv,
    float* __restrict__ qT, float* __restrict__ kT, float* __restrict__ vT,
    float* __restrict__ ekt, float* __restrict__ evt)
{
    __shared__ float smem[16 * 34 + 16 * 64];
    int tid = threadIdx.x;

    if (blockIdx.x >= 384) {
        // ---- edge tables ----
        int t = blockIdx.x - 384;
        float* se = smem;
        se[tid] = emb[t * Cdim + tid];
        __syncthreads();
        float a = 0.f, b = 0.f;
        for (int k = 0; k < Cdim; ++k) {
            float ev = se[k];
            a = fmaf(ev, wk[k * Cdim + tid], a);
            b = fmaf(ev, wv[k * Cdim + tid], b);
        }
        ekt[t * Cdim + tid] = a;
        evt[t * Cdim + tid] = b;
        return;
    }

    const int N = 3 * Cdim;
    const int K = Cdim;
    float (*As)[34] = (float(*)[34])smem;
    float (*Bs)[64] = (float(*)[64])(smem + 16 * 34);
    int m0 = (blockIdx.x / 12) * 32;
    int n0 = (blockIdx.x % 12) * 64;
    int tr = tid >> 4, tc = tid & 15;
    float acc[2][4] = {};
    int bkr = tid >> 4, bcq = (tid & 15) * 4;

    for (int k0 = 0; k0 < K; k0 += 16) {
        if (tid < 128) {
            int r = tid >> 2, kq = (tid & 3) * 4;
            float4 av = *(const float4*)(A + (size_t)(m0 + r) * K + k0 + kq);
            As[kq + 0][r] = av.x;
            As[kq + 1][r] = av.y;
            As[kq + 2][r] = av.z;
            As[kq + 3][r] = av.w;
        }
        float4 bv = *(const float4*)(Bw + (size_t)(k0 + bkr) * N + n0 + bcq);
        *(float4*)&Bs[bkr][bcq] = bv;
        __syncthreads();
#pragma unroll
        for (int kk = 0; kk < 16; ++kk) {
            float2 a2 = *(float2*)&As[kk][tr * 2];
            float4 b4 = *(float4*)&Bs[kk][tc * 4];
            acc[0][0] = fmaf(a2.x, b4.x, acc[0][0]);
            acc[0][1] = fmaf(a2.x, b4.y, acc[0][1]);
            acc[0][2] = fmaf(a2.x, b4.z, acc[0][2]);
            acc[0][3] = fmaf(a2.x, b4.w, acc[0][3]);
            acc[1][0] = fmaf(a2.y, b4.x, acc[1][0]);
            acc[1][1] = fmaf(a2.y, b4.y, acc[1][1]);
            acc[1][2] = fmaf(a2.y, b4.z, acc[1][2]);
            acc[1][3] = fmaf(a2.y, b4.w, acc[1][3]);
        }
        __syncthreads();
    }
    int sec = n0 >> 8;
    float* dst = (sec == 0) ? qT : (sec == 1) ? kT : vT;
    int cc0 = (n0 & 255) + tc * 4;
    int h = cc0 >> 5;
    int e0 = cc0 & 31;
#pragma unroll
    for (int i = 0; i < 2; ++i) {
        int m = m0 + tr * 2 + i;
        int bq = m >> 9, t = m & (Tdim - 1);
        float4 val = make_float4(acc[i][0], acc[i][1], acc[i][2], acc[i][3]);
        *(float4*)&dst[(((size_t)bq * Hdim + h) * Tdim + t) * Edim + e0] = val;
    }
}

// ---------------------------------------------------------------------------
// Kernel 2: attention. Round-12 change: OCCUPANCY. R11 post-mortem: dbuf gave
// 0 gain (attn 42.4us, VALUBusy 24%, HBM 9.5%, occupancy 35%) -> stall-bound
// with only 2 blocks/CU AND only 2 blocks of work per CU (grid 512 = 2x256).
// New: 1 rep per block (grid 1024, global heavy-first LPT order), qm
// premultiply REMOVED (pass A reads sekt gather + wave-uniform sq broadcast,
// +4 v_mul/eq — R10's known cost, bought back by occupancy), kv single-buffer
// 16KB with register prefetch (T14: loads issued before compute, LDS-written
// after the read-fence barrier). spart overlays ss. LDS 42.8KB + VGPR<=80
// via __launch_bounds__(512,6) -> 3 blocks/CU resident, 6 waves/SIMD.
// WATCH: VGPR_Count must be <= 80; >80 => 5 waves/SIMD => 2 blocks => revert.
// Do NOT: kv dbuf at 2 blocks/CU (R11: 0 gain), register-held multi-tile
// prefetch (R4: spill), online softmax (R7-R9), fp16 scores/probs (numerics).
// ---------------------------------------------------------------------------
__global__ __launch_bounds__(512, 6) void attn_kernel(
    const float* __restrict__ qT, const float* __restrict__ kT,
    const float* __restrict__ vT, const int* __restrict__ bm,
    const float* __restrict__ ekt, const float* __restrict__ evt,
    const float* __restrict__ abt, float* __restrict__ y)
{
    __shared__ float kv[JT][32];                 // k or v tile, swizzled (16K)
    __shared__ float ss[TI][516];                // scores -> probs (16.5K)
    __shared__ unsigned int st1pf[Tdim];         // nibbles of bm[b,j,i0+ii]
    __shared__ unsigned int st2pf[Tdim];         // nibbles of bm[b,i0+ii,j]
    __shared__ float sekt[NTYPES][36];
    __shared__ float sevt[NTYPES][36];
    __shared__ float sq[TI][36];
    __shared__ float sabt[NTYPES];
    __shared__ float sinv[TI];
    // total ~42.8 KB -> 3 blocks/CU

    float* spart = (float*)ss;                   // overlay AFTER pass B done

    // global LPT order: heaviest tau (njt=4) blocks dispatch first
    const int tau = 63 - (blockIdx.x >> 4);
    const int bh = blockIdx.x & 15;
    const int h = bh & (Hdim - 1);
    const int b = bh >> 3;
    const int tid = threadIdx.x;
    const int wave = tid >> 6;
    const int lane = tid & 63;
    const float inv_scale = 0.17677669529663687f;  // 1/sqrt(32)

    const float* qbase = qT + (size_t)bh * Tdim * Edim;
    const float* kbase = kT + (size_t)bh * Tdim * Edim;
    const float* vbase = vT + (size_t)bh * Tdim * Edim;
    const int* bmb = bm + (size_t)b * Tdim * Tdim;

    // staging geometry: each thread owns rows sr0 and sr0+64, one quad each
    const int sr0 = tid >> 3;                 // 0..63
    const int seq4 = (tid & 7) << 2;          // quad offset in floats
    const int ssw = seq4 ^ ((sr0 & 7) << 2);  // swizzled (same for sr0+64)

    const int i0 = tau * TI;
    const int imax = i0 + TI - 1;
    const int njt = (imax >> 7) + 1;
    const int jmax = njt << 7;

    if (tid < 128) {
        int t = tid >> 3, eq = tid & 7;
        *(float4*)&sekt[t][eq * 4] = *(const float4*)&ekt[t * Cdim + h * Edim + eq * 4];
        *(float4*)&sevt[t][eq * 4] = *(const float4*)&evt[t * Cdim + h * Edim + eq * 4];
    }
    if (tid < NTYPES) sabt[tid] = abt[tid * Hdim + h];
    // stage q rows
    if (tid < TI * 8) {
        int r = tid >> 3, eq = tid & 7;
        *(float4*)&sq[r][eq * 4] =
            *(const float4*)&qbase[(size_t)(i0 + r) * Edim + eq * 4];
    }
    // stage both nibble tables
    if (tid < jmax) {
        const int* rowp = bmb + (size_t)tid * Tdim + i0;
        int4 lo = *(const int4*)rowp;
        int4 hi = *(const int4*)(rowp + 4);
        st1pf[tid] =
            ((unsigned)(lo.x & 15)) | (((unsigned)(lo.y & 15)) << 4) |
            (((unsigned)(lo.z & 15)) << 8) | (((unsigned)(lo.w & 15)) << 12) |
            (((unsigned)(hi.x & 15)) << 16) | (((unsigned)(hi.y & 15)) << 20) |
            (((unsigned)(hi.z & 15)) << 24) | (((unsigned)(hi.w & 15)) << 28);
        unsigned w2 = 0;
#pragma unroll
        for (int iiq = 0; iiq < 8; ++iiq)
            w2 |= ((unsigned)(bmb[(size_t)(i0 + iiq) * Tdim + tid] & 15)) << (iiq * 4);
        st2pf[tid] = w2;
    }
    // stage k-tile 0 directly (no prior readers)
    *(float4*)&kv[sr0][ssw] = *(const float4*)&kbase[((size_t)sr0 << 5) + seq4];
    *(float4*)&kv[sr0 + 64][ssw] =
        *(const float4*)&kbase[(((size_t)sr0 + 64) << 5) + seq4];
    __syncthreads();

    // ---------------- Pass A: scores (single buffer, reg prefetch) ----------
    for (int jt = 0; jt < njt; ++jt) {
        int j0 = jt << 7;
        // prefetch next k-tile, or v-tile 0 on the last pass-A tile
        const float* nsrc =
            (jt + 1 < njt) ? (kbase + ((size_t)(j0 + 128) << 5)) : vbase;
        float4 n0 = *(const float4*)(nsrc + ((size_t)sr0 << 5) + seq4);
        float4 n1 = *(const float4*)(nsrc + (((size_t)sr0 + 64) << 5) + seq4);

        int jsub = wave & 1;
        int jl = (jsub << 6) + lane;
        int j = j0 + jl;
        const int xsw = (jl & 7) << 2;
        float4 k4[8];
#pragma unroll
        for (int eq = 0; eq < 8; ++eq)
            k4[eq] = *(float4*)&kv[jl][(eq << 2) ^ xsw];
        unsigned tp = st1pf[j];
        unsigned tp2 = st2pf[j];

#pragma unroll
        for (int u = 0; u < 2; ++u) {
            int ii = (wave >> 1) + (u << 2);
            int i = i0 + ii;
            if (j0 + (jsub << 6) > i) continue;   // wave-uniform skip
            int t1 = (tp >> (ii * 4)) & 15;
            int t2 = (tp2 >> (ii * 4)) & 15;
            float s0 = 0.f, s1 = 0.f;
#pragma unroll
            for (int eq = 0; eq < 8; ++eq) {
                float4 qv = *(float4*)&sq[ii][eq * 4];      // uniform broadcast
                float4 ee = *(float4*)&sekt[t1][eq * 4];    // type gather
                s0 = fmaf(qv.x * k4[eq].x, ee.x, s0);
                s1 = fmaf(qv.y * k4[eq].y, ee.y, s1);
                s0 = fmaf(qv.z * k4[eq].z, ee.z, s0);
                s1 = fmaf(qv.w * k4[eq].w, ee.w, s1);
            }
            if (j <= i) ss[ii][j] = (s0 + s1) * inv_scale + sabt[t2];
        }
        __syncthreads();          // all kv reads + this tile's ss writes done
        *(float4*)&kv[sr0][ssw] = n0;
        *(float4*)&kv[sr0 + 64][ssw] = n1;
        if (jt + 1 < njt) __syncthreads();   // last tile: post-softmax bar covers
    }
    // kv now holds v-tile 0 (visible after next barrier); all scores written

    // ---------------- softmax (normalization deferred) ----------------
    {
        int ii = wave;
        int i = i0 + ii;
        float m = -1e30f;
        for (int j = lane; j <= i; j += 64) m = fmaxf(m, ss[ii][j]);
        for (int off = 32; off; off >>= 1) m = fmaxf(m, __shfl_xor(m, off));
        float sum = 0.f;
        for (int j = lane; j <= i; j += 64) {
            float p = __expf(ss[ii][j] - m);
            ss[ii][j] = p;
            sum += p;
        }
        for (int off = 32; off; off >>= 1) sum += __shfl_xor(sum, off);
        if (lane == 0) sinv[ii] = 1.0f / sum;
    }
    __syncthreads();       // v0 + probs + sinv visible

    // ---------------- Pass B: PV (single buffer, reg prefetch) --------------
    float4 acc[TI];
#pragma unroll
    for (int ii = 0; ii < TI; ++ii) acc[ii] = make_float4(0.f, 0.f, 0.f, 0.f);
    int gid = tid >> 3;        // 64 groups of 8
    int eqg4 = (tid & 7) << 2;
    for (int jt = 0; jt < njt; ++jt) {
        int j0 = jt << 7;
        const bool pf = (jt + 1) < njt;
        float4 n0, n1;
        if (pf) {
            const float* nsrc = vbase + ((size_t)(j0 + 128) << 5);
            n0 = *(const float4*)(nsrc + ((size_t)sr0 << 5) + seq4);
            n1 = *(const float4*)(nsrc + (((size_t)sr0 + 64) << 5) + seq4);
        }
#pragma unroll
        for (int sub = 0; sub < 2; ++sub) {
            int jl = (sub << 6) + gid;
            int j = j0 + jl;
            float4 v4 = *(float4*)&kv[jl][eqg4 ^ ((jl & 7) << 2)];
            unsigned tp = st1pf[j];
#pragma unroll
            for (int ii = 0; ii < TI; ++ii) {
                int i = i0 + ii;
                if (j0 + (sub << 6) > i) continue;  // block-uniform skip
                float p = (j <= i) ? ss[ii][j] : 0.f;
                int t1 = (tp >> (ii * 4)) & 15;
                float4 ev = *(float4*)&sevt[t1][eqg4];
                acc[ii].x = fmaf(p * ev.x, v4.x, acc[ii].x);
                acc[ii].y = fmaf(p * ev.y, v4.y, acc[ii].y);
                acc[ii].z = fmaf(p * ev.z, v4.z, acc[ii].z);
                acc[ii].w = fmaf(p * ev.w, v4.w, acc[ii].w);
            }
        }
        __syncthreads();      // kv reads done; last tile: ss reads done too
        if (pf) {
            *(float4*)&kv[sr0][ssw] = n0;
            *(float4*)&kv[sr0 + 64][ssw] = n1;
            __syncthreads();
        }
    }
    // reduce across the wave's 8 groups (lane bits 3,4,5)
#pragma unroll
    for (int ii = 0; ii < TI; ++ii) {
#pragma unroll
        for (int m = 8; m <= 32; m <<= 1) {
            acc[ii].x += __shfl_xor(acc[ii].x, m);
            acc[ii].y += __shfl_xor(acc[ii].y, m);
            acc[ii].z += __shfl_xor(acc[ii].z, m);
            acc[ii].w += __shfl_xor(acc[ii].w, m);
        }
    }
    // spart overlays ss: all ss reads ended before the last pass-B barrier
    if (lane < 8) {
#pragma unroll
        for (int ii = 0; ii < TI; ++ii)
            *(float4*)&spart[((wave * TI + ii) << 5) + lane * 4] = acc[ii];
    }
    __syncthreads();
    if (tid < TI * Edim) {
        int ii = tid >> 5, e = tid & 31;
        float yv = 0.f;
#pragma unroll
        for (int w = 0; w < 8; ++w) yv += spart[((w * TI + ii) << 5) + e];
        yv *= sinv[ii];
        y[((size_t)(b * Tdim + i0 + ii)) * Cdim + h * Edim + e] = yv;
    }
}

// ---------------------------------------------------------------------------
// Kernel 3: proj GEMM (M=1024, K=256, N=256) -> d_out (B,T,C), 32x64 tiles
// ---------------------------------------------------------------------------
__global__ __launch_bounds__(256) void proj_gemm_kernel(
    const float* __restrict__ A, const float* __restrict__ Bw,
    float* __restrict__ out)
{
    const int N = Cdim;
    const int K = Cdim;
    __shared__ float As[16][34];
    __shared__ float Bs[16][64];
    int m0 = blockIdx.y * 32;
    int n0 = blockIdx.x * 64;
    int tid = threadIdx.x;
    int tr = tid >> 4, tc = tid & 15;
    float acc[2][4] = {};
    int bkr = tid >> 4, bcq = (tid & 15) * 4;

    for (int k0 = 0; k0 < K; k0 += 16) {
        if (tid < 128) {
            int r = tid >> 2, kq = (tid & 3) * 4;
            float4 av = *(const float4*)(A + (size_t)(m0 + r) * K + k0 + kq);
            As[kq + 0][r] = av.x;
            As[kq + 1][r] = av.y;
            As[kq + 2][r] = av.z;
            As[kq + 3][r] = av.w;
        }
        float4 bv = *(const float4*)(Bw + (size_t)(k0 + bkr) * N + n0 + bcq);
        *(float4*)&Bs[bkr][bcq] = bv;
        __syncthreads();
#pragma unroll
        for (int kk = 0; kk < 16; ++kk) {
            float2 a2 = *(float2*)&As[kk][tr * 2];
            float4 b4 = *(float4*)&Bs[kk][tc * 4];
            acc[0][0] = fmaf(a2.x, b4.x, acc[0][0]);
            acc[0][1] = fmaf(a2.x, b4.y, acc[0][1]);
            acc[0][2] = fmaf(a2.x, b4.z, acc[0][2]);
            acc[0][3] = fmaf(a2.x, b4.w, acc[0][3]);
            acc[1][0] = fmaf(a2.y, b4.x, acc[1][0]);
            acc[1][1] = fmaf(a2.y, b4.y, acc[1][1]);
            acc[1][2] = fmaf(a2.y, b4.z, acc[1][2]);
            acc[1][3] = fmaf(a2.y, b4.w, acc[1][3]);
        }
        __syncthreads();
    }
#pragma unroll
    for (int i = 0; i < 2; ++i) {
        int m = m0 + tr * 2 + i;
        float4 val = make_float4(acc[i][0], acc[i][1], acc[i][2], acc[i][3]);
        *(float4*)&out[(size_t)m * N + n0 + tc * 4] = val;
    }
}

// ---------------------------------------------------------------------------
extern "C" void kernel_launch(void* const* d_in, const int* in_sizes, int n_in,
                              void* d_out, int out_size, void* d_ws, size_t ws_size,
                              hipStream_t stream) {
    (void)in_sizes; (void)n_in; (void)out_size; (void)ws_size;
    const float* x = (const float*)d_in[0];
    const int* bias_matrix = (const int*)d_in[1];
    const float* w_attn = (const float*)d_in[2];
    const float* w_proj = (const float*)d_in[3];
    const float* w_edge_k = (const float*)d_in[4];
    const float* w_edge_v = (const float*)d_in[5];
    const float* edge_emb = (const float*)d_in[6];
    const float* attn_bias = (const float*)d_in[7];
    float* out = (float*)d_out;

    const size_t n_qkv = (size_t)Bdim * Hdim * Tdim * Edim;
    float* ws = (float*)d_ws;
    float* qT = ws;
    float* kT = qT + n_qkv;
    float* vT = kT + n_qkv;
    float* y = vT + n_qkv;
    float* ekt = y + (size_t)Bdim * Tdim * Cdim;
    float* evt = ekt + (size_t)NTYPES * Cdim;

    pre_kernel<<<400, 256, 0, stream>>>(x, w_attn, edge_emb, w_edge_k, w_edge_v,
                                        qT, kT, vT, ekt, evt);
    attn_kernel<<<dim3(64 * 16), 512, 0, stream>>>(qT, kT, vT, bias_matrix,
                                                   ekt, evt, attn_bias, y);
    proj_gemm_kernel<<<dim3(4, 32), 256, 0, stream>>>(y, w_proj, out);
}

// Round 3
// 131.886 us; speedup vs baseline: 1.2533x; 1.2533x over previous
//
#include <hip/hip_runtime.h>
#include <hip/hip_bf16.h>
#include <math.h>

// Problem constants
#define Bdim 2
#define Tdim 512
#define Cdim 256
#define Hdim 8
#define Edim 32
#define NTYPES 16
#define TI 8       // i-tile size
#define JT 128     // j-tile size

// ---------------------------------------------------------------------------
// Kernel 1: fused edge-tables + qkv GEMM.
// blocks 0..383: qkv GEMM (M=1024,K=256,N=768), 32x64 tile, scatter (B,H,T,E)
// blocks 384..399: ekt/evt = emb[t] @ w_edge_{k,v}
// ---------------------------------------------------------------------------
__global__ __launch_bounds__(256) void pre_kernel(
    const float* __restrict__ A, const float* __restrict__ Bw,
    const float* __restrict__ emb, const float* __restrict__ wk,
    const float* __restrict__ wv,
    float* __restrict__ qT, float* __restrict__ kT, float* __restrict__ vT,
    float* __restrict__ ekt, float* __restrict__ evt)
{
    __shared__ float smem[16 * 34 + 16 * 64];
    int tid = threadIdx.x;

    if (blockIdx.x >= 384) {
        // ---- edge tables ----
        int t = blockIdx.x - 384;
        float* se = smem;
        se[tid] = emb[t * Cdim + tid];
        __syncthreads();
        float a = 0.f, b = 0.f;
        for (int k = 0; k < Cdim; ++k) {
            float ev = se[k];
            a = fmaf(ev, wk[k * Cdim + tid], a);
            b = fmaf(ev, wv[k * Cdim + tid], b);
        }
        ekt[t * Cdim + tid] = a;
        evt[t * Cdim + tid] = b;
        return;
    }

    const int N = 3 * Cdim;
    const int K = Cdim;
    float (*As)[34] = (float(*)[34])smem;
    float (*Bs)[64] = (float(*)[64])(smem + 16 * 34);
    int m0 = (blockIdx.x / 12) * 32;
    int n0 = (blockIdx.x % 12) * 64;
    int tr = tid >> 4, tc = tid & 15;
    float acc[2][4] = {};
    int bkr = tid >> 4, bcq = (tid & 15) * 4;

    for (int k0 = 0; k0 < K; k0 += 16) {
        if (tid < 128) {
            int r = tid >> 2, kq = (tid & 3) * 4;
            float4 av = *(const float4*)(A + (size_t)(m0 + r) * K + k0 + kq);
            As[kq + 0][r] = av.x;
            As[kq + 1][r] = av.y;
            As[kq + 2][r] = av.z;
            As[kq + 3][r] = av.w;
        }
        float4 bv = *(const float4*)(Bw + (size_t)(k0 + bkr) * N + n0 + bcq);
        *(float4*)&Bs[bkr][bcq] = bv;
        __syncthreads();
#pragma unroll
        for (int kk = 0; kk < 16; ++kk) {
            float2 a2 = *(float2*)&As[kk][tr * 2];
            float4 b4 = *(float4*)&Bs[kk][tc * 4];
            acc[0][0] = fmaf(a2.x, b4.x, acc[0][0]);
            acc[0][1] = fmaf(a2.x, b4.y, acc[0][1]);
            acc[0][2] = fmaf(a2.x, b4.z, acc[0][2]);
            acc[0][3] = fmaf(a2.x, b4.w, acc[0][3]);
            acc[1][0] = fmaf(a2.y, b4.x, acc[1][0]);
            acc[1][1] = fmaf(a2.y, b4.y, acc[1][1]);
            acc[1][2] = fmaf(a2.y, b4.z, acc[1][2]);
            acc[1][3] = fmaf(a2.y, b4.w, acc[1][3]);
        }
        __syncthreads();
    }
    int sec = n0 >> 8;
    float* dst = (sec == 0) ? qT : (sec == 1) ? kT : vT;
    int cc0 = (n0 & 255) + tc * 4;
    int h = cc0 >> 5;
    int e0 = cc0 & 31;
#pragma unroll
    for (int i = 0; i < 2; ++i) {
        int m = m0 + tr * 2 + i;
        int bq = m >> 9, t = m & (Tdim - 1);
        float4 val = make_float4(acc[i][0], acc[i][1], acc[i][2], acc[i][3]);
        *(float4*)&dst[(((size_t)bq * Hdim + h) * Tdim + t) * Edim + e0] = val;
    }
}

// ---------------------------------------------------------------------------
// Kernel 2: attention. Round-13: occupancy WITHOUT the register cap.
// R12 post-mortem: (512,6) forced VGPR 40 -> k4[8]+acc[8] spilled to scratch,
// 161MB HBM traffic @2.2TB/s = the whole runtime. Occupancy mechanism itself
// worked (35->53%). Fix: keep (512,4) (R1 allocated 64 VGPR naturally; HW
// runs 3 blocks/CU by itself when VGPR<=84 and LDS<=53.3KB), keep grid 1024
// (1 rep/block, LPT heavy-first), shrink LDS to 53.6KB with qm RETAINED:
//   - qm [8][16][32] XOR-swizzled (quad ^= (t&7)<<2), same 2-way conflicts
//   - ss [8][512] unpadded (all 3 access patterns conflict-free by audit)
//   - sq/sekt deleted: qm built directly from global q/ekt (L1 absorbs)
//   - st2pf deleted: bias types re-read from global bm in softmax (coalesced,
//     L2-resident; fixed 8-iter unrolled loop keeps tb[8] in registers)
// WATCH: VGPR must be <=84; >84 silently falls to 2 blocks/CU (~R1 perf).
// Do NOT: min-waves>4 (R7+R12: 40-VGPR catastrophic spill, twice confirmed),
// kv dbuf at 2 blocks/CU (R11: 0 gain), online softmax (R7-R9), qm removal
// at 2-block occupancy (R10: +3us VALU).
// ---------------------------------------------------------------------------
__global__ __launch_bounds__(512, 4) void attn_kernel(
    const float* __restrict__ qT, const float* __restrict__ kT,
    const float* __restrict__ vT, const int* __restrict__ bm,
    const float* __restrict__ ekt, const float* __restrict__ evt,
    const float* __restrict__ abt, float* __restrict__ y)
{
    __shared__ float kv[JT][32];                 // k or v tile, swizzled (16K)
    __shared__ float qm[TI][NTYPES][32];         // q*ekt, XOR-swizzled (16K)
    __shared__ float ss[TI][512];                // scores -> probs (16K)
    __shared__ unsigned int st1pf[Tdim];         // nibbles of bm[b,j,i0+ii] (2K)
    __shared__ float sevt[NTYPES][36];           // (2.25K)
    __shared__ float sabt[NTYPES];
    __shared__ float sinv[TI];
    // total ~53.6 KB -> 3 blocks/CU at VGPR<=84

    float* spart = (float*)ss;                   // overlay AFTER pass B done

    // global LPT order: heaviest tau (njt=4) blocks dispatch first
    const int tau = 63 - (blockIdx.x >> 4);
    const int bh = blockIdx.x & 15;
    const int h = bh & (Hdim - 1);
    const int b = bh >> 3;
    const int tid = threadIdx.x;
    const int wave = tid >> 6;
    const int lane = tid & 63;
    const float inv_scale = 0.17677669529663687f;  // 1/sqrt(32)

    const float* qbase = qT + (size_t)bh * Tdim * Edim;
    const float* kbase = kT + (size_t)bh * Tdim * Edim;
    const float* vbase = vT + (size_t)bh * Tdim * Edim;
    const int* bmb = bm + (size_t)b * Tdim * Tdim;

    // staging geometry: each thread owns rows sr0 and sr0+64, one quad each
    const int sr0 = tid >> 3;                 // 0..63
    const int seq4 = (tid & 7) << 2;          // quad offset in floats
    const int ssw = seq4 ^ ((sr0 & 7) << 2);  // swizzled (same for sr0+64)

    const int i0 = tau * TI;
    const int imax = i0 + TI - 1;
    const int njt = (imax >> 7) + 1;
    const int jmax = njt << 7;

    if (tid < 128) {
        int t = tid >> 3, eq = tid & 7;
        *(float4*)&sevt[t][eq * 4] = *(const float4*)&evt[t * Cdim + h * Edim + eq * 4];
    }
    if (tid < NTYPES) sabt[tid] = abt[tid * Hdim + h];
    // stage nibble table st1pf[j]: bm[b, j, i0..i0+7]
    if (tid < jmax) {
        const int* rowp = bmb + (size_t)tid * Tdim + i0;
        int4 lo = *(const int4*)rowp;
        int4 hi = *(const int4*)(rowp + 4);
        st1pf[tid] =
            ((unsigned)(lo.x & 15)) | (((unsigned)(lo.y & 15)) << 4) |
            (((unsigned)(lo.z & 15)) << 8) | (((unsigned)(lo.w & 15)) << 12) |
            (((unsigned)(hi.x & 15)) << 16) | (((unsigned)(hi.y & 15)) << 20) |
            (((unsigned)(hi.z & 15)) << 24) | (((unsigned)(hi.w & 15)) << 28);
    }
    // stage k-tile 0 (no prior readers)
    *(float4*)&kv[sr0][ssw] = *(const float4*)&kbase[((size_t)sr0 << 5) + seq4];
    *(float4*)&kv[sr0 + 64][ssw] =
        *(const float4*)&kbase[(((size_t)sr0 + 64) << 5) + seq4];
    // build qm[ii][t] = q[i0+ii] * ekt[t] directly from global (L1 absorbs
    // the x16 q-row and x8 ekt-row redundancy)
    for (int idx = tid; idx < TI * NTYPES * 8; idx += 512) {
        int eq = idx & 7;
        int t = (idx >> 3) & (NTYPES - 1);
        int r = idx >> 7;
        float4 qv = *(const float4*)&qbase[(size_t)(i0 + r) * Edim + eq * 4];
        float4 ev = *(const float4*)&ekt[t * Cdim + h * Edim + eq * 4];
        float4 o;
        o.x = qv.x * ev.x; o.y = qv.y * ev.y;
        o.z = qv.z * ev.z; o.w = qv.w * ev.w;
        *(float4*)&qm[r][t][(eq << 2) ^ ((t & 7) << 2)] = o;
    }
    __syncthreads();   // kv0 + qm + st1pf + sevt + sabt ready

    // ---------------- Pass A: scores (single buffer, reg prefetch) ----------
    for (int jt = 0; jt < njt; ++jt) {
        int j0 = jt << 7;
        // prefetch next k-tile, or v-tile 0 on the last pass-A tile
        const float* nsrc =
            (jt + 1 < njt) ? (kbase + ((size_t)(j0 + 128) << 5)) : vbase;
        float4 n0 = *(const float4*)(nsrc + ((size_t)sr0 << 5) + seq4);
        float4 n1 = *(const float4*)(nsrc + (((size_t)sr0 + 64) << 5) + seq4);

        int jsub = wave & 1;
        int jl = (jsub << 6) + lane;
        int j = j0 + jl;
        const int xsw = (jl & 7) << 2;
        float4 k4[8];
#pragma unroll
        for (int eq = 0; eq < 8; ++eq)
            k4[eq] = *(float4*)&kv[jl][(eq << 2) ^ xsw];
        unsigned tp = st1pf[j];

#pragma unroll
        for (int u = 0; u < 2; ++u) {
            int ii = (wave >> 1) + (u << 2);
            int i = i0 + ii;
            if (j0 + (jsub << 6) > i) continue;   // wave-uniform skip
            int t1 = (tp >> (ii * 4)) & 15;
            const int qsw = (t1 & 7) << 2;
            float s0 = 0.f, s1 = 0.f;
#pragma unroll
            for (int eq = 0; eq < 8; ++eq) {
                float4 qv = *(float4*)&qm[ii][t1][(eq << 2) ^ qsw];
                s0 = fmaf(qv.x, k4[eq].x, s0);
                s1 = fmaf(qv.y, k4[eq].y, s1);
                s0 = fmaf(qv.z, k4[eq].z, s0);
                s1 = fmaf(qv.w, k4[eq].w, s1);
            }
            if (j <= i) ss[ii][j] = (s0 + s1) * inv_scale;
        }
        __syncthreads();          // all kv reads + this tile's ss writes done
        *(float4*)&kv[sr0][ssw] = n0;
        *(float4*)&kv[sr0 + 64][ssw] = n1;
        if (jt + 1 < njt) __syncthreads();   // last tile: post-softmax bar covers
    }
    // kv now holds v-tile 0 (visible after next barrier); all scores written

    // ------- softmax (bias added here from global bm; norm deferred) -------
    {
        int ii = wave;
        int i = i0 + ii;
        const int* brow = bmb + (size_t)i * Tdim;   // bm[b, i, :], coalesced
        float tb[8];
        float m = -1e30f;
#pragma unroll
        for (int c = 0; c < 8; ++c) {
            int j = (c << 6) + lane;                // always < Tdim: safe read
            float val = ss[ii][j] + sabt[brow[j] & 15];
            tb[c] = (j <= i) ? val : -1e30f;        // select AFTER add: no NaN
            m = fmaxf(m, tb[c]);
        }
        for (int off = 32; off; off >>= 1) m = fmaxf(m, __shfl_xor(m, off));
        float sum = 0.f;
#pragma unroll
        for (int c = 0; c < 8; ++c) {
            int j = (c << 6) + lane;
            float p = __expf(tb[c] - m);
            p = (j <= i) ? p : 0.f;                 // kill exp(0)=1 of idle lanes
            sum += p;
            if (j <= i) ss[ii][j] = p;
        }
        for (int off = 32; off; off >>= 1) sum += __shfl_xor(sum, off);
        if (lane == 0) sinv[ii] = 1.0f / sum;
    }
    __syncthreads();       // v0 + probs + sinv visible

    // ---------------- Pass B: PV (single buffer, reg prefetch) --------------
    float4 acc[TI];
#pragma unroll
    for (int ii = 0; ii < TI; ++ii) acc[ii] = make_float4(0.f, 0.f, 0.f, 0.f);
    int gid = tid >> 3;        // 64 groups of 8
    int eqg4 = (tid & 7) << 2;
    for (int jt = 0; jt < njt; ++jt) {
        int j0 = jt << 7;
        const bool pf = (jt + 1) < njt;
        float4 n0, n1;
        if (pf) {
            const float* nsrc = vbase + ((size_t)(j0 + 128) << 5);
            n0 = *(const float4*)(nsrc + ((size_t)sr0 << 5) + seq4);
            n1 = *(const float4*)(nsrc + (((size_t)sr0 + 64) << 5) + seq4);
        }
#pragma unroll
        for (int sub = 0; sub < 2; ++sub) {
            int jl = (sub << 6) + gid;
            int j = j0 + jl;
            float4 v4 = *(float4*)&kv[jl][eqg4 ^ ((jl & 7) << 2)];
            unsigned tp = st1pf[j];
#pragma unroll
            for (int ii = 0; ii < TI; ++ii) {
                int i = i0 + ii;
                if (j0 + (sub << 6) > i) continue;  // block-uniform skip
                float p = (j <= i) ? ss[ii][j] : 0.f;
                int t1 = (tp >> (ii * 4)) & 15;
                float4 ev = *(float4*)&sevt[t1][eqg4];
                acc[ii].x = fmaf(p * ev.x, v4.x, acc[ii].x);
                acc[ii].y = fmaf(p * ev.y, v4.y, acc[ii].y);
                acc[ii].z = fmaf(p * ev.z, v4.z, acc[ii].z);
                acc[ii].w = fmaf(p * ev.w, v4.w, acc[ii].w);
            }
        }
        __syncthreads();      // kv reads done; last tile: ss reads done too
        if (pf) {
            *(float4*)&kv[sr0][ssw] = n0;
            *(float4*)&kv[sr0 + 64][ssw] = n1;
            __syncthreads();
        }
    }
    // reduce across the wave's 8 groups (lane bits 3,4,5)
#pragma unroll
    for (int ii = 0; ii < TI; ++ii) {
#pragma unroll
        for (int m = 8; m <= 32; m <<= 1) {
            acc[ii].x += __shfl_xor(acc[ii].x, m);
            acc[ii].y += __shfl_xor(acc[ii].y, m);
            acc[ii].z += __shfl_xor(acc[ii].z, m);
            acc[ii].w += __shfl_xor(acc[ii].w, m);
        }
    }
    // spart overlays ss: all ss reads ended before the last pass-B barrier
    if (lane < 8) {
#pragma unroll
        for (int ii = 0; ii < TI; ++ii)
            *(float4*)&spart[((wave * TI + ii) << 5) + lane * 4] = acc[ii];
    }
    __syncthreads();
    if (tid < TI * Edim) {
        int ii = tid >> 5, e = tid & 31;
        float yv = 0.f;
#pragma unroll
        for (int w = 0; w < 8; ++w) yv += spart[((w * TI + ii) << 5) + e];
        yv *= sinv[ii];
        y[((size_t)(b * Tdim + i0 + ii)) * Cdim + h * Edim + e] = yv;
    }
}

// ---------------------------------------------------------------------------
// Kernel 3: proj GEMM (M=1024, K=256, N=256) -> d_out (B,T,C), 32x64 tiles
// ---------------------------------------------------------------------------
__global__ __launch_bounds__(256) void proj_gemm_kernel(
    const float* __restrict__ A, const float* __restrict__ Bw,
    float* __restrict__ out)
{
    const int N = Cdim;
    const int K = Cdim;
    __shared__ float As[16][34];
    __shared__ float Bs[16][64];
    int m0 = blockIdx.y * 32;
    int n0 = blockIdx.x * 64;
    int tid = threadIdx.x;
    int tr = tid >> 4, tc = tid & 15;
    float acc[2][4] = {};
    int bkr = tid >> 4, bcq = (tid & 15) * 4;

    for (int k0 = 0; k0 < K; k0 += 16) {
        if (tid < 128) {
            int r = tid >> 2, kq = (tid & 3) * 4;
            float4 av = *(const float4*)(A + (size_t)(m0 + r) * K + k0 + kq);
            As[kq + 0][r] = av.x;
            As[kq + 1][r] = av.y;
            As[kq + 2][r] = av.z;
            As[kq + 3][r] = av.w;
        }
        float4 bv = *(const float4*)(Bw + (size_t)(k0 + bkr) * N + n0 + bcq);
        *(float4*)&Bs[bkr][bcq] = bv;
        __syncthreads();
#pragma unroll
        for (int kk = 0; kk < 16; ++kk) {
            float2 a2 = *(float2*)&As[kk][tr * 2];
            float4 b4 = *(float4*)&Bs[kk][tc * 4];
            acc[0][0] = fmaf(a2.x, b4.x, acc[0][0]);
            acc[0][1] = fmaf(a2.x, b4.y, acc[0][1]);
            acc[0][2] = fmaf(a2.x, b4.z, acc[0][2]);
            acc[0][3] = fmaf(a2.x, b4.w, acc[0][3]);
            acc[1][0] = fmaf(a2.y, b4.x, acc[1][0]);
            acc[1][1] = fmaf(a2.y, b4.y, acc[1][1]);
            acc[1][2] = fmaf(a2.y, b4.z, acc[1][2]);
            acc[1][3] = fmaf(a2.y, b4.w, acc[1][3]);
        }
        __syncthreads();
    }
#pragma unroll
    for (int i = 0; i < 2; ++i) {
        int m = m0 + tr * 2 + i;
        float4 val = make_float4(acc[i][0], acc[i][1], acc[i][2], acc[i][3]);
        *(float4*)&out[(size_t)m * N + n0 + tc * 4] = val;
    }
}

// ---------------------------------------------------------------------------
extern "C" void kernel_launch(void* const* d_in, const int* in_sizes, int n_in,
                              void* d_out, int out_size, void* d_ws, size_t ws_size,
                              hipStream_t stream) {
    (void)in_sizes; (void)n_in; (void)out_size; (void)ws_size;
    const float* x = (const float*)d_in[0];
    const int* bias_matrix = (const int*)d_in[1];
    const float* w_attn = (const float*)d_in[2];
    const float* w_proj = (const float*)d_in[3];
    const float* w_edge_k = (const float*)d_in[4];
    const float* w_edge_v = (const float*)d_in[5];
    const float* edge_emb = (const float*)d_in[6];
    const float* attn_bias = (const float*)d_in[7];
    float* out = (float*)d_out;

    const size_t n_qkv = (size_t)Bdim * Hdim * Tdim * Edim;
    float* ws = (float*)d_ws;
    float* qT = ws;
    float* kT = qT + n_qkv;
    float* vT = kT + n_qkv;
    float* y = vT + n_qkv;
    float* ekt = y + (size_t)Bdim * Tdim * Cdim;
    float* evt = ekt + (size_t)NTYPES * Cdim;

    pre_kernel<<<400, 256, 0, stream>>>(x, w_attn, edge_emb, w_edge_k, w_edge_v,
                                        qT, kT, vT, ekt, evt);
    attn_kernel<<<dim3(64 * 16), 512, 0, stream>>>(qT, kT, vT, bias_matrix,
                                                   ekt, evt, attn_bias, y);
    proj_gemm_kernel<<<dim3(4, 32), 256, 0, stream>>>(y, w_proj, out);
}